// Round 2
// baseline (857.276 us; speedup 1.0000x reference)
//
#include <hip/hip_runtime.h>
#include <hip/hip_bf16.h>
#include <math.h>

// Problem constants
#define N_TOK 4096
#define C_DIM 1024
#define H_DIM 4096
#define NEXP 7          // dynamic experts
#define NGRP 8          // 7 dynamic + 1 static
#define HCAP 13184      // max padded entries: <=13177, rounded up

typedef __attribute__((ext_vector_type(8))) short short8;
typedef __attribute__((ext_vector_type(4))) float floatx4;

// ---- workspace layout (bytes) ----
static const size_t OFF_COUNTS = 0;                                  // int[8]
static const size_t OFF_CURSOR = 64;                                 // int[8]
static const size_t OFF_BASE   = 128;                                // int[8]
static const size_t OFF_PCOUNT = 192;                                // int[8]
static const size_t OFF_CNT8   = 256;                                // int[8]
static const size_t OFF_USAGE  = 320;                                // float[8]
static const size_t OFF_TOPKI  = 4096;                               // int[8192]
static const size_t OFF_TOPKW  = OFF_TOPKI + 8192ull * 4;            // float[8192]
static const size_t OFF_ETOK   = OFF_TOPKW + 8192ull * 4;            // int[HCAP]
static const size_t OFF_EWT    = OFF_ETOK + (size_t)HCAP * 4;        // float[HCAP]
static const size_t OFF_XB     = 262144;                             // bf16[N*C]
static const size_t OFF_W1T    = OFF_XB + (size_t)N_TOK * C_DIM * 2; // bf16[8][H][C]
static const size_t OFF_W2T    = OFF_W1T + (size_t)NGRP * H_DIM * C_DIM * 2; // bf16[8][C][H]
static const size_t OFF_H      = OFF_W2T + (size_t)NGRP * C_DIM * H_DIM * 2; // bf16[HCAP][H]

static __device__ __forceinline__ unsigned short f2bf(float f) {
    __hip_bfloat16 b = __float2bfloat16(f);
    return *reinterpret_cast<unsigned short*>(&b);
}

static __device__ __forceinline__ void gll16(const void* g, void* l) {
    __builtin_amdgcn_global_load_lds((const __attribute__((address_space(1))) void*)g,
                                     (__attribute__((address_space(3))) void*)l, 16, 0, 0);
}

// ---------------- small init ----------------
__global__ void init_small_kernel(int* counts, int* cursor, float* usage) {
    int i = threadIdx.x;
    if (i < 8) { counts[i] = 0; cursor[i] = 0; usage[i] = 0.f; }
}

__global__ void zero_out_kernel(float* y, int n) {
    int i = blockIdx.x * blockDim.x + threadIdx.x;
    int stride = gridDim.x * blockDim.x;
    for (; i < n; i += stride) y[i] = 0.f;
}

// ---------------- x fp32 -> bf16 ----------------
__global__ void convert_x_kernel(const float* __restrict__ x, unsigned short* __restrict__ xb) {
    int i = blockIdx.x * 256 + threadIdx.x;   // i < N*C/4
    float4 v = ((const float4*)x)[i];
    ushort4 o;
    o.x = f2bf(v.x); o.y = f2bf(v.y); o.z = f2bf(v.z); o.w = f2bf(v.w);
    ((ushort4*)xb)[i] = o;
}

// ---------------- transpose + convert: src[R,S] fp32 -> dst[S,R] bf16, 8 experts ----
// tile: 64 rows (R) x 32 cols (S); writes are 128B-wide (64 consecutive bf16)
__global__ __launch_bounds__(256) void transpose_cvt_kernel(
    const float* __restrict__ dyn, const float* __restrict__ stat,
    __hip_bfloat16* __restrict__ dst, int R, int S)
{
    int e = blockIdx.z;
    const float* src = (e < NEXP) ? (dyn + (size_t)e * R * S) : stat;
    __hip_bfloat16* d = dst + (size_t)e * R * S;
    int s0 = blockIdx.x * 32, r0 = blockIdx.y * 64;
    int tx = threadIdx.x & 31, ty = threadIdx.x >> 5; // 32 x 8
    __shared__ float t[64][33];
#pragma unroll
    for (int i = 0; i < 8; i++) {
        int r = ty + i * 8;
        t[r][tx] = src[(size_t)(r0 + r) * S + s0 + tx];
    }
    __syncthreads();
    int tx2 = threadIdx.x & 63, ty2 = threadIdx.x >> 6; // 64 x 4
#pragma unroll
    for (int i = 0; i < 8; i++) {
        int s = ty2 + i * 4;
        d[(size_t)(s0 + s) * R + r0 + tx2] = __float2bfloat16(t[tx2][s]);
    }
}

// ---------------- gating: one wave per token ----------------
__global__ __launch_bounds__(256) void gate_kernel(
    const float* __restrict__ x, const float* __restrict__ gw,
    int* __restrict__ topki, float* __restrict__ topkw,
    int* counts, float* usage)
{
    int wid = threadIdx.x >> 6, lane = threadIdx.x & 63;
    int t = blockIdx.x * 4 + wid;
    float s[NEXP];
#pragma unroll
    for (int e = 0; e < NEXP; e++) s[e] = 0.f;
    for (int c = lane; c < C_DIM; c += 64) {
        float xv = x[(size_t)t * C_DIM + c];
#pragma unroll
        for (int e = 0; e < NEXP; e++) s[e] += xv * gw[c * NEXP + e];
    }
#pragma unroll
    for (int e = 0; e < NEXP; e++)
        for (int off = 32; off > 0; off >>= 1) s[e] += __shfl_xor(s[e], off);
    if (lane == 0) {
        int e0 = 0;
        for (int e = 1; e < NEXP; e++) if (s[e] > s[e0]) e0 = e;
        int e1 = -1;
        for (int e = 0; e < NEXP; e++) {
            if (e == e0) continue;
            if (e1 < 0 || s[e] > s[e1]) e1 = e;
        }
        float w0 = 1.f / (1.f + expf(s[e1] - s[e0]));
        float w1 = 1.f - w0;
        topki[t * 2] = e0; topki[t * 2 + 1] = e1;
        topkw[t * 2] = w0; topkw[t * 2 + 1] = w1;
        atomicAdd(&counts[e0], 1); atomicAdd(&counts[e1], 1);
        atomicAdd(&usage[e0], w0); atomicAdd(&usage[e1], w1);
    }
}

// ---------------- prefix: group bases, pads, static entries, aux loss ----------------
__global__ __launch_bounds__(256) void prefix_kernel(
    const int* counts, const float* usage,
    int* base, int* pcount, int* cnt8,
    int* etok, float* ewt, float* y, int aux_index)
{
    __shared__ int sb[NGRP], sc[NGRP], sp[NGRP];
    if (threadIdx.x == 0) {
        int run = 0;
        for (int g = 0; g < NEXP; g++) {
            int c = counts[g];
            int p = (c + 127) & ~127;
            base[g] = run; pcount[g] = p; cnt8[g] = c;
            sb[g] = run; sc[g] = c; sp[g] = p;
            run += p;
        }
        base[NEXP] = run; pcount[NEXP] = N_TOK; cnt8[NEXP] = N_TOK;
        sb[NEXP] = run; sc[NEXP] = N_TOK; sp[NEXP] = N_TOK;
        // aux = 0.01 * variance(expert_usage)
        float u[NEXP]; float mean = 0.f;
        for (int e = 0; e < NEXP; e++) { u[e] = usage[e] / (float)N_TOK; mean += u[e]; }
        mean /= (float)NEXP;
        float var = 0.f;
        for (int e = 0; e < NEXP; e++) { float d = u[e] - mean; var += d * d; }
        var /= (float)NEXP;
        y[aux_index] = 0.01f * var;
    }
    __syncthreads();
    // static group entries: token == position, weight 1
    for (int i = threadIdx.x; i < N_TOK; i += 256) {
        etok[sb[NEXP] + i] = i; ewt[sb[NEXP] + i] = 1.0f;
    }
    // pad entries: token 0, weight 0
    for (int g = 0; g < NEXP; g++) {
        for (int i = sc[g] + (int)threadIdx.x; i < sp[g]; i += 256) {
            etok[sb[g] + i] = 0; ewt[sb[g] + i] = 0.f;
        }
    }
}

// ---------------- scatter into compact entry lists ----------------
__global__ void scatter_kernel(const int* __restrict__ topki, const float* __restrict__ topkw,
                               const int* __restrict__ base, int* cursor,
                               int* __restrict__ etok, float* __restrict__ ewt)
{
    int i = blockIdx.x * 256 + threadIdx.x;   // < 8192
    int t = i >> 1;
    int e = topki[i];
    float w = topkw[i];
    int pos = atomicAdd(&cursor[e], 1);
    int idx = base[e] + pos;
    etok[idx] = t; ewt[idx] = w;
}

// ---------------- grouped GEMM1: h = gelu(X @ W1[g]) ----------------
// grid: (H/128, 64, 8); block 256 (4 waves, 2x2 over 128x128 tile)
__global__ __launch_bounds__(256) void gemm1_kernel(
    const __hip_bfloat16* __restrict__ xb,
    const __hip_bfloat16* __restrict__ w1t,   // [8][H][C]
    __hip_bfloat16* __restrict__ h,           // [HCAP][H]
    const int* __restrict__ etok,
    const int* __restrict__ base,
    const int* __restrict__ pcount)
{
    int g = blockIdx.z, mt = blockIdx.y, ct = blockIdx.x;
    if (mt * 128 >= pcount[g]) return;
    int eb = base[g];

    __shared__ __align__(16) __hip_bfloat16 Als[128 * 32];
    __shared__ __align__(16) __hip_bfloat16 Bls[128 * 32];

    int tid = threadIdx.x;
    int lane = tid & 63, wid = tid >> 6;
    int quad = lane >> 4, l16 = lane & 15;
    int wm = wid >> 1, wn = wid & 1;
    int rsub = lane >> 2, chunk = lane & 3;

    const char* gA[2]; const char* gB[2];
    char* lA[2]; char* lB[2];
#pragma unroll
    for (int j = 0; j < 2; j++) {
        int rowA = wid * 32 + j * 16 + rsub;
        int tok = etok[eb + mt * 128 + rowA];
        gA[j] = (const char*)(xb + (size_t)tok * C_DIM) + chunk * 16;
        lA[j] = (char*)Als + (wid * 32 + j * 16) * 64;
        int rowB = wid * 32 + j * 16 + rsub;
        gB[j] = (const char*)(w1t + ((size_t)g * H_DIM + ct * 128 + rowB) * C_DIM) + chunk * 16;
        lB[j] = (char*)Bls + (wid * 32 + j * 16) * 64;
    }

    floatx4 acc[4][4] = {};
    for (int k0 = 0; k0 < C_DIM; k0 += 32) {
        size_t koff = (size_t)k0 * 2;
        gll16(gA[0] + koff, lA[0]);
        gll16(gA[1] + koff, lA[1]);
        gll16(gB[0] + koff, lB[0]);
        gll16(gB[1] + koff, lB[1]);
        __syncthreads();
        short8 a[4], b[4];
#pragma unroll
        for (int i = 0; i < 4; i++) {
            a[i] = *(const short8*)((const char*)Als + (((wm * 64 + i * 16 + l16) * 32 + quad * 8) * 2));
            b[i] = *(const short8*)((const char*)Bls + (((wn * 64 + i * 16 + l16) * 32 + quad * 8) * 2));
        }
#pragma unroll
        for (int i = 0; i < 4; i++)
#pragma unroll
            for (int j = 0; j < 4; j++)
                acc[i][j] = __builtin_amdgcn_mfma_f32_16x16x32_bf16(a[i], b[j], acc[i][j], 0, 0, 0);
        __syncthreads();
    }

    // epilogue: exact gelu, bf16 store to h (pad rows stored too — weight 0 later)
#pragma unroll
    for (int i = 0; i < 4; i++) {
        int rbase = mt * 128 + wm * 64 + i * 16 + quad * 4;
#pragma unroll
        for (int reg = 0; reg < 4; reg++) {
            size_t hrow = (size_t)(eb + rbase + reg) * H_DIM;
#pragma unroll
            for (int j = 0; j < 4; j++) {
                int cc = ct * 128 + wn * 64 + j * 16 + l16;
                float v = acc[i][j][reg];
                float ge = 0.5f * v * (1.0f + erff(v * 0.70710678118654752f));
                h[hrow + cc] = __float2bfloat16(ge);
            }
        }
    }
}

// ---------------- grouped GEMM2: y[token] += w * (H @ W2[g]) ----------------
// split-K=2: blockIdx.y = mt*2 + khalf; grid: (C/128, 128, 8); block 256
__global__ __launch_bounds__(256) void gemm2_kernel(
    const __hip_bfloat16* __restrict__ h,
    const __hip_bfloat16* __restrict__ w2t,   // [8][C][H]
    float* __restrict__ y,
    const int* __restrict__ etok,
    const float* __restrict__ ewt,
    const int* __restrict__ base,
    const int* __restrict__ pcount,
    const int* __restrict__ cnt8)
{
    int g = blockIdx.z, ct = blockIdx.x;
    int mt = blockIdx.y >> 1, kh = blockIdx.y & 1;
    if (mt * 128 >= pcount[g]) return;
    int eb = base[g];
    int cnt = cnt8[g];

    __shared__ __align__(16) __hip_bfloat16 Als[128 * 32];
    __shared__ __align__(16) __hip_bfloat16 Bls[128 * 32];

    int tid = threadIdx.x;
    int lane = tid & 63, wid = tid >> 6;
    int quad = lane >> 4, l16 = lane & 15;
    int wm = wid >> 1, wn = wid & 1;
    int rsub = lane >> 2, chunk = lane & 3;

    const char* gA[2]; const char* gB[2];
    char* lA[2]; char* lB[2];
#pragma unroll
    for (int j = 0; j < 2; j++) {
        int rowA = wid * 32 + j * 16 + rsub;
        gA[j] = (const char*)(h + (size_t)(eb + mt * 128 + rowA) * H_DIM) + chunk * 16;
        lA[j] = (char*)Als + (wid * 32 + j * 16) * 64;
        int rowB = wid * 32 + j * 16 + rsub;
        gB[j] = (const char*)(w2t + ((size_t)g * C_DIM + ct * 128 + rowB) * H_DIM) + chunk * 16;
        lB[j] = (char*)Bls + (wid * 32 + j * 16) * 64;
    }

    floatx4 acc[4][4] = {};
    int kbeg = kh * (H_DIM / 2), kend = kbeg + (H_DIM / 2);
    for (int k0 = kbeg; k0 < kend; k0 += 32) {
        size_t koff = (size_t)k0 * 2;
        gll16(gA[0] + koff, lA[0]);
        gll16(gA[1] + koff, lA[1]);
        gll16(gB[0] + koff, lB[0]);
        gll16(gB[1] + koff, lB[1]);
        __syncthreads();
        short8 a[4], b[4];
#pragma unroll
        for (int i = 0; i < 4; i++) {
            a[i] = *(const short8*)((const char*)Als + (((wm * 64 + i * 16 + l16) * 32 + quad * 8) * 2));
            b[i] = *(const short8*)((const char*)Bls + (((wn * 64 + i * 16 + l16) * 32 + quad * 8) * 2));
        }
#pragma unroll
        for (int i = 0; i < 4; i++)
#pragma unroll
            for (int j = 0; j < 4; j++)
                acc[i][j] = __builtin_amdgcn_mfma_f32_16x16x32_bf16(a[i], b[j], acc[i][j], 0, 0, 0);
        __syncthreads();
    }

    // epilogue: weighted atomicAdd into y (skip pad rows); split-K partials combine via atomics
#pragma unroll
    for (int i = 0; i < 4; i++) {
        int rl0 = mt * 128 + wm * 64 + i * 16 + quad * 4;
#pragma unroll
        for (int reg = 0; reg < 4; reg++) {
            int rl = rl0 + reg;
            if (rl < cnt) {
                int entry = eb + rl;
                float w = ewt[entry];
                int tok = etok[entry];
                size_t yrow = (size_t)tok * C_DIM;
#pragma unroll
                for (int j = 0; j < 4; j++) {
                    int cc = ct * 128 + wn * 64 + j * 16 + l16;
                    atomicAdd(&y[yrow + cc], acc[i][j][reg] * w);
                }
            }
        }
    }
}

extern "C" void kernel_launch(void* const* d_in, const int* in_sizes, int n_in,
                              void* d_out, int out_size, void* d_ws, size_t ws_size,
                              hipStream_t stream) {
    const float* x      = (const float*)d_in[0];
    const float* gate_w = (const float*)d_in[1];
    const float* w1     = (const float*)d_in[2];
    const float* w2     = (const float*)d_in[3];
    const float* w1s    = (const float*)d_in[4];
    const float* w2s    = (const float*)d_in[5];
    float* y = (float*)d_out;
    char* ws = (char*)d_ws;

    int*   counts = (int*)(ws + OFF_COUNTS);
    int*   cursor = (int*)(ws + OFF_CURSOR);
    int*   base   = (int*)(ws + OFF_BASE);
    int*   pcount = (int*)(ws + OFF_PCOUNT);
    int*   cnt8   = (int*)(ws + OFF_CNT8);
    float* usage  = (float*)(ws + OFF_USAGE);
    int*   topki  = (int*)(ws + OFF_TOPKI);
    float* topkw  = (float*)(ws + OFF_TOPKW);
    int*   etok   = (int*)(ws + OFF_ETOK);
    float* ewt    = (float*)(ws + OFF_EWT);
    unsigned short* xb_u = (unsigned short*)(ws + OFF_XB);
    __hip_bfloat16* xb  = (__hip_bfloat16*)(ws + OFF_XB);
    __hip_bfloat16* w1t = (__hip_bfloat16*)(ws + OFF_W1T);
    __hip_bfloat16* w2t = (__hip_bfloat16*)(ws + OFF_W2T);
    __hip_bfloat16* hbuf = (__hip_bfloat16*)(ws + OFF_H);

    init_small_kernel<<<1, 64, 0, stream>>>(counts, cursor, usage);
    zero_out_kernel<<<2048, 256, 0, stream>>>(y, out_size);

    convert_x_kernel<<<(N_TOK * C_DIM / 4) / 256, 256, 0, stream>>>(x, xb_u);
    // w1 [C,H] -> w1t [H,C]; w1s likewise as expert 7
    transpose_cvt_kernel<<<dim3(H_DIM / 32, C_DIM / 64, NGRP), 256, 0, stream>>>(w1, w1s, w1t, C_DIM, H_DIM);
    // w2 [H,C] -> w2t [C,H]; w2s likewise as expert 7
    transpose_cvt_kernel<<<dim3(C_DIM / 32, H_DIM / 64, NGRP), 256, 0, stream>>>(w2, w2s, w2t, H_DIM, C_DIM);

    gate_kernel<<<N_TOK / 4, 256, 0, stream>>>(x, gate_w, topki, topkw, counts, usage);
    prefix_kernel<<<1, 256, 0, stream>>>(counts, usage, base, pcount, cnt8, etok, ewt, y, N_TOK * C_DIM);
    scatter_kernel<<<(N_TOK * 2) / 256, 256, 0, stream>>>(topki, topkw, base, cursor, etok, ewt);

    gemm1_kernel<<<dim3(H_DIM / 128, 64, NGRP), 256, 0, stream>>>(xb, w1t, hbuf, etok, base, pcount);
    gemm2_kernel<<<dim3(C_DIM / 128, 128, NGRP), 256, 0, stream>>>(hbuf, w2t, y, etok, ewt, base, pcount, cnt8);
}

// Round 3
// 838.057 us; speedup vs baseline: 1.0229x; 1.0229x over previous
//
#include <hip/hip_runtime.h>
#include <hip/hip_bf16.h>
#include <math.h>

// Problem constants
#define N_TOK 4096
#define C_DIM 1024
#define H_DIM 4096
#define NEXP 7          // dynamic experts
#define NGRP 8          // 7 dynamic + 1 static
#define HCAP 13184      // max padded entries: <=13177, rounded up

typedef __attribute__((ext_vector_type(8))) short short8;
typedef __attribute__((ext_vector_type(4))) float floatx4;

// ---- workspace layout (bytes) ----
static const size_t OFF_COUNTS = 0;                                  // int[8]
static const size_t OFF_CURSOR = 64;                                 // int[8]
static const size_t OFF_BASE   = 128;                                // int[8]
static const size_t OFF_PCOUNT = 192;                                // int[8]
static const size_t OFF_CNT8   = 256;                                // int[8]
static const size_t OFF_USAGE  = 320;                                // float[8]
static const size_t OFF_TOPKI  = 4096;                               // int[8192]
static const size_t OFF_TOPKW  = OFF_TOPKI + 8192ull * 4;            // float[8192]
static const size_t OFF_ETOK   = OFF_TOPKW + 8192ull * 4;            // int[HCAP]
static const size_t OFF_EWT    = OFF_ETOK + (size_t)HCAP * 4;        // float[HCAP]
static const size_t OFF_XB     = 262144;                             // bf16[N*C]
static const size_t OFF_W1T    = OFF_XB + (size_t)N_TOK * C_DIM * 2; // bf16[8][H][C]
static const size_t OFF_W2T    = OFF_W1T + (size_t)NGRP * H_DIM * C_DIM * 2; // bf16[8][C][H]
static const size_t OFF_H      = OFF_W2T + (size_t)NGRP * C_DIM * H_DIM * 2; // bf16[HCAP][H]

static __device__ __forceinline__ unsigned short f2bf(float f) {
    __hip_bfloat16 b = __float2bfloat16(f);
    return *reinterpret_cast<unsigned short*>(&b);
}

static __device__ __forceinline__ void gll16(const void* g, void* l) {
    __builtin_amdgcn_global_load_lds((const __attribute__((address_space(1))) void*)g,
                                     (__attribute__((address_space(3))) void*)l, 16, 0, 0);
}

// ---------------- small init ----------------
__global__ void init_small_kernel(int* counts, int* cursor, float* usage) {
    int i = threadIdx.x;
    if (i < 8) { counts[i] = 0; cursor[i] = 0; usage[i] = 0.f; }
}

__global__ void zero_out_kernel(float* y, int n) {
    int i = blockIdx.x * blockDim.x + threadIdx.x;
    int stride = gridDim.x * blockDim.x;
    for (; i < n; i += stride) y[i] = 0.f;
}

// ---------------- x fp32 -> bf16 ----------------
__global__ void convert_x_kernel(const float* __restrict__ x, unsigned short* __restrict__ xb) {
    int i = blockIdx.x * 256 + threadIdx.x;   // i < N*C/4
    float4 v = ((const float4*)x)[i];
    ushort4 o;
    o.x = f2bf(v.x); o.y = f2bf(v.y); o.z = f2bf(v.z); o.w = f2bf(v.w);
    ((ushort4*)xb)[i] = o;
}

// ---------------- transpose + convert: src[R,S] fp32 -> dst[S,R] bf16, 8 experts ----
// tile: 64 rows (R) x 32 cols (S); writes are 128B-wide (64 consecutive bf16)
__global__ __launch_bounds__(256) void transpose_cvt_kernel(
    const float* __restrict__ dyn, const float* __restrict__ stat,
    __hip_bfloat16* __restrict__ dst, int R, int S)
{
    int e = blockIdx.z;
    const float* src = (e < NEXP) ? (dyn + (size_t)e * R * S) : stat;
    __hip_bfloat16* d = dst + (size_t)e * R * S;
    int s0 = blockIdx.x * 32, r0 = blockIdx.y * 64;
    int tx = threadIdx.x & 31, ty = threadIdx.x >> 5; // 32 x 8
    __shared__ float t[64][33];
#pragma unroll
    for (int i = 0; i < 8; i++) {
        int r = ty + i * 8;
        t[r][tx] = src[(size_t)(r0 + r) * S + s0 + tx];
    }
    __syncthreads();
    int tx2 = threadIdx.x & 63, ty2 = threadIdx.x >> 6; // 64 x 4
#pragma unroll
    for (int i = 0; i < 8; i++) {
        int s = ty2 + i * 4;
        d[(size_t)(s0 + s) * R + r0 + tx2] = __float2bfloat16(t[tx2][s]);
    }
}

// ---------------- gating: one wave per token ----------------
__global__ __launch_bounds__(256) void gate_kernel(
    const float* __restrict__ x, const float* __restrict__ gw,
    int* __restrict__ topki, float* __restrict__ topkw,
    int* counts, float* usage)
{
    int wid = threadIdx.x >> 6, lane = threadIdx.x & 63;
    int t = blockIdx.x * 4 + wid;
    float s[NEXP];
#pragma unroll
    for (int e = 0; e < NEXP; e++) s[e] = 0.f;
    for (int c = lane; c < C_DIM; c += 64) {
        float xv = x[(size_t)t * C_DIM + c];
#pragma unroll
        for (int e = 0; e < NEXP; e++) s[e] += xv * gw[c * NEXP + e];
    }
#pragma unroll
    for (int e = 0; e < NEXP; e++)
        for (int off = 32; off > 0; off >>= 1) s[e] += __shfl_xor(s[e], off);
    if (lane == 0) {
        int e0 = 0;
        for (int e = 1; e < NEXP; e++) if (s[e] > s[e0]) e0 = e;
        int e1 = -1;
        for (int e = 0; e < NEXP; e++) {
            if (e == e0) continue;
            if (e1 < 0 || s[e] > s[e1]) e1 = e;
        }
        float w0 = 1.f / (1.f + expf(s[e1] - s[e0]));
        float w1 = 1.f - w0;
        topki[t * 2] = e0; topki[t * 2 + 1] = e1;
        topkw[t * 2] = w0; topkw[t * 2 + 1] = w1;
        atomicAdd(&counts[e0], 1); atomicAdd(&counts[e1], 1);
        atomicAdd(&usage[e0], w0); atomicAdd(&usage[e1], w1);
    }
}

// ---------------- prefix: group bases, pads, static entries, aux loss ----------------
__global__ __launch_bounds__(256) void prefix_kernel(
    const int* counts, const float* usage,
    int* base, int* pcount, int* cnt8,
    int* etok, float* ewt, float* y, int aux_index)
{
    __shared__ int sb[NGRP], sc[NGRP], sp[NGRP];
    if (threadIdx.x == 0) {
        int run = 0;
        for (int g = 0; g < NEXP; g++) {
            int c = counts[g];
            int p = (c + 127) & ~127;
            base[g] = run; pcount[g] = p; cnt8[g] = c;
            sb[g] = run; sc[g] = c; sp[g] = p;
            run += p;
        }
        base[NEXP] = run; pcount[NEXP] = N_TOK; cnt8[NEXP] = N_TOK;
        sb[NEXP] = run; sc[NEXP] = N_TOK; sp[NEXP] = N_TOK;
        // aux = 0.01 * variance(expert_usage)
        float u[NEXP]; float mean = 0.f;
        for (int e = 0; e < NEXP; e++) { u[e] = usage[e] / (float)N_TOK; mean += u[e]; }
        mean /= (float)NEXP;
        float var = 0.f;
        for (int e = 0; e < NEXP; e++) { float d = u[e] - mean; var += d * d; }
        var /= (float)NEXP;
        y[aux_index] = 0.01f * var;
    }
    __syncthreads();
    // static group entries: token == position, weight 1
    for (int i = threadIdx.x; i < N_TOK; i += 256) {
        etok[sb[NEXP] + i] = i; ewt[sb[NEXP] + i] = 1.0f;
    }
    // pad entries: token 0, weight 0
    for (int g = 0; g < NEXP; g++) {
        for (int i = sc[g] + (int)threadIdx.x; i < sp[g]; i += 256) {
            etok[sb[g] + i] = 0; ewt[sb[g] + i] = 0.f;
        }
    }
}

// ---------------- scatter into compact entry lists ----------------
__global__ void scatter_kernel(const int* __restrict__ topki, const float* __restrict__ topkw,
                               const int* __restrict__ base, int* cursor,
                               int* __restrict__ etok, float* __restrict__ ewt)
{
    int i = blockIdx.x * 256 + threadIdx.x;   // < 8192
    int t = i >> 1;
    int e = topki[i];
    float w = topkw[i];
    int pos = atomicAdd(&cursor[e], 1);
    int idx = base[e] + pos;
    etok[idx] = t; ewt[idx] = w;
}

// ---------------- grouped GEMM1: h = gelu(X @ W1[g]) ----------------
// BK=64 staged as 2x 8KB panels; grid: (H/128, 64, 8); block 256
__global__ __launch_bounds__(256) void gemm1_kernel(
    const __hip_bfloat16* __restrict__ xb,
    const __hip_bfloat16* __restrict__ w1t,   // [8][H][C]
    __hip_bfloat16* __restrict__ h,           // [HCAP][H]
    const int* __restrict__ etok,
    const int* __restrict__ base,
    const int* __restrict__ pcount)
{
    int g = blockIdx.z, mt = blockIdx.y, ct = blockIdx.x;
    if (mt * 128 >= pcount[g]) return;
    int eb = base[g];

    // two BK=32 panels each for A and B: [2][128 rows][32 k] bf16 = 2 x 8KB
    __shared__ __align__(16) char AlsB[2 * 8192];
    __shared__ __align__(16) char BlsB[2 * 8192];

    int tid = threadIdx.x;
    int lane = tid & 63, wid = tid >> 6;
    int quad = lane >> 4, l16 = lane & 15;
    int wm = wid >> 1, wn = wid & 1;
    int rsub = lane >> 2, chunk = lane & 3;

    const char* gA[2]; const char* gB[2];
    char* lA[2]; char* lB[2];
#pragma unroll
    for (int j = 0; j < 2; j++) {
        int rowA = wid * 32 + j * 16 + rsub;
        int tok = etok[eb + mt * 128 + rowA];
        gA[j] = (const char*)(xb + (size_t)tok * C_DIM) + chunk * 16;
        lA[j] = AlsB + (wid * 32 + j * 16) * 64;
        int rowB = wid * 32 + j * 16 + rsub;
        gB[j] = (const char*)(w1t + ((size_t)g * H_DIM + ct * 128 + rowB) * C_DIM) + chunk * 16;
        lB[j] = BlsB + (wid * 32 + j * 16) * 64;
    }

    floatx4 acc[4][4] = {};
    for (int k0 = 0; k0 < C_DIM; k0 += 64) {
        size_t koff = (size_t)k0 * 2;
#pragma unroll
        for (int s = 0; s < 2; s++) {
            size_t so = koff + (size_t)s * 64;   // 32 k-elems * 2B
            gll16(gA[0] + so, lA[0] + s * 8192);
            gll16(gA[1] + so, lA[1] + s * 8192);
            gll16(gB[0] + so, lB[0] + s * 8192);
            gll16(gB[1] + so, lB[1] + s * 8192);
        }
        __syncthreads();
#pragma unroll
        for (int s = 0; s < 2; s++) {
            short8 a[4], b[4];
#pragma unroll
            for (int i = 0; i < 4; i++) {
                a[i] = *(const short8*)(AlsB + s * 8192 + (((wm * 64 + i * 16 + l16) * 32 + quad * 8) * 2));
                b[i] = *(const short8*)(BlsB + s * 8192 + (((wn * 64 + i * 16 + l16) * 32 + quad * 8) * 2));
            }
#pragma unroll
            for (int i = 0; i < 4; i++)
#pragma unroll
                for (int j = 0; j < 4; j++)
                    acc[i][j] = __builtin_amdgcn_mfma_f32_16x16x32_bf16(a[i], b[j], acc[i][j], 0, 0, 0);
        }
        __syncthreads();
    }

    // epilogue: exact gelu, bf16 store to h (pad rows stored too — weight 0 later)
#pragma unroll
    for (int i = 0; i < 4; i++) {
        int rbase = mt * 128 + wm * 64 + i * 16 + quad * 4;
#pragma unroll
        for (int reg = 0; reg < 4; reg++) {
            size_t hrow = (size_t)(eb + rbase + reg) * H_DIM;
#pragma unroll
            for (int j = 0; j < 4; j++) {
                int cc = ct * 128 + wn * 64 + j * 16 + l16;
                float v = acc[i][j][reg];
                float ge = 0.5f * v * (1.0f + erff(v * 0.70710678118654752f));
                h[hrow + cc] = __float2bfloat16(ge);
            }
        }
    }
}

// ---------------- grouped GEMM2: y[token] += w * (H @ W2[g]) ----------------
// BK=64 staged as 2x 8KB panels; grid: (C/128, 64, 8); block 256
__global__ __launch_bounds__(256) void gemm2_kernel(
    const __hip_bfloat16* __restrict__ h,
    const __hip_bfloat16* __restrict__ w2t,   // [8][C][H]
    float* __restrict__ y,
    const int* __restrict__ etok,
    const float* __restrict__ ewt,
    const int* __restrict__ base,
    const int* __restrict__ pcount,
    const int* __restrict__ cnt8)
{
    int g = blockIdx.z, ct = blockIdx.x, mt = blockIdx.y;
    if (mt * 128 >= pcount[g]) return;
    int eb = base[g];
    int cnt = cnt8[g];

    __shared__ __align__(16) char AlsB[2 * 8192];
    __shared__ __align__(16) char BlsB[2 * 8192];

    int tid = threadIdx.x;
    int lane = tid & 63, wid = tid >> 6;
    int quad = lane >> 4, l16 = lane & 15;
    int wm = wid >> 1, wn = wid & 1;
    int rsub = lane >> 2, chunk = lane & 3;

    const char* gA[2]; const char* gB[2];
    char* lA[2]; char* lB[2];
#pragma unroll
    for (int j = 0; j < 2; j++) {
        int rowA = wid * 32 + j * 16 + rsub;
        gA[j] = (const char*)(h + (size_t)(eb + mt * 128 + rowA) * H_DIM) + chunk * 16;
        lA[j] = AlsB + (wid * 32 + j * 16) * 64;
        int rowB = wid * 32 + j * 16 + rsub;
        gB[j] = (const char*)(w2t + ((size_t)g * C_DIM + ct * 128 + rowB) * H_DIM) + chunk * 16;
        lB[j] = BlsB + (wid * 32 + j * 16) * 64;
    }

    floatx4 acc[4][4] = {};
    for (int k0 = 0; k0 < H_DIM; k0 += 64) {
        size_t koff = (size_t)k0 * 2;
#pragma unroll
        for (int s = 0; s < 2; s++) {
            size_t so = koff + (size_t)s * 64;
            gll16(gA[0] + so, lA[0] + s * 8192);
            gll16(gA[1] + so, lA[1] + s * 8192);
            gll16(gB[0] + so, lB[0] + s * 8192);
            gll16(gB[1] + so, lB[1] + s * 8192);
        }
        __syncthreads();
#pragma unroll
        for (int s = 0; s < 2; s++) {
            short8 a[4], b[4];
#pragma unroll
            for (int i = 0; i < 4; i++) {
                a[i] = *(const short8*)(AlsB + s * 8192 + (((wm * 64 + i * 16 + l16) * 32 + quad * 8) * 2));
                b[i] = *(const short8*)(BlsB + s * 8192 + (((wn * 64 + i * 16 + l16) * 32 + quad * 8) * 2));
            }
#pragma unroll
            for (int i = 0; i < 4; i++)
#pragma unroll
                for (int j = 0; j < 4; j++)
                    acc[i][j] = __builtin_amdgcn_mfma_f32_16x16x32_bf16(a[i], b[j], acc[i][j], 0, 0, 0);
        }
        __syncthreads();
    }

    // epilogue: weighted atomicAdd into y (skip pad rows)
#pragma unroll
    for (int i = 0; i < 4; i++) {
        int rl0 = mt * 128 + wm * 64 + i * 16 + quad * 4;
#pragma unroll
        for (int reg = 0; reg < 4; reg++) {
            int rl = rl0 + reg;
            if (rl < cnt) {
                int entry = eb + rl;
                float w = ewt[entry];
                int tok = etok[entry];
                size_t yrow = (size_t)tok * C_DIM;
#pragma unroll
                for (int j = 0; j < 4; j++) {
                    int cc = ct * 128 + wn * 64 + j * 16 + l16;
                    atomicAdd(&y[yrow + cc], acc[i][j][reg] * w);
                }
            }
        }
    }
}

extern "C" void kernel_launch(void* const* d_in, const int* in_sizes, int n_in,
                              void* d_out, int out_size, void* d_ws, size_t ws_size,
                              hipStream_t stream) {
    const float* x      = (const float*)d_in[0];
    const float* gate_w = (const float*)d_in[1];
    const float* w1     = (const float*)d_in[2];
    const float* w2     = (const float*)d_in[3];
    const float* w1s    = (const float*)d_in[4];
    const float* w2s    = (const float*)d_in[5];
    float* y = (float*)d_out;
    char* ws = (char*)d_ws;

    int*   counts = (int*)(ws + OFF_COUNTS);
    int*   cursor = (int*)(ws + OFF_CURSOR);
    int*   base   = (int*)(ws + OFF_BASE);
    int*   pcount = (int*)(ws + OFF_PCOUNT);
    int*   cnt8   = (int*)(ws + OFF_CNT8);
    float* usage  = (float*)(ws + OFF_USAGE);
    int*   topki  = (int*)(ws + OFF_TOPKI);
    float* topkw  = (float*)(ws + OFF_TOPKW);
    int*   etok   = (int*)(ws + OFF_ETOK);
    float* ewt    = (float*)(ws + OFF_EWT);
    unsigned short* xb_u = (unsigned short*)(ws + OFF_XB);
    __hip_bfloat16* xb  = (__hip_bfloat16*)(ws + OFF_XB);
    __hip_bfloat16* w1t = (__hip_bfloat16*)(ws + OFF_W1T);
    __hip_bfloat16* w2t = (__hip_bfloat16*)(ws + OFF_W2T);
    __hip_bfloat16* hbuf = (__hip_bfloat16*)(ws + OFF_H);

    init_small_kernel<<<1, 64, 0, stream>>>(counts, cursor, usage);
    zero_out_kernel<<<2048, 256, 0, stream>>>(y, out_size);

    convert_x_kernel<<<(N_TOK * C_DIM / 4) / 256, 256, 0, stream>>>(x, xb_u);
    // w1 [C,H] -> w1t [H,C]; w1s likewise as expert 7
    transpose_cvt_kernel<<<dim3(H_DIM / 32, C_DIM / 64, NGRP), 256, 0, stream>>>(w1, w1s, w1t, C_DIM, H_DIM);
    // w2 [H,C] -> w2t [C,H]; w2s likewise as expert 7
    transpose_cvt_kernel<<<dim3(C_DIM / 32, H_DIM / 64, NGRP), 256, 0, stream>>>(w2, w2s, w2t, H_DIM, C_DIM);

    gate_kernel<<<N_TOK / 4, 256, 0, stream>>>(x, gate_w, topki, topkw, counts, usage);
    prefix_kernel<<<1, 256, 0, stream>>>(counts, usage, base, pcount, cnt8, etok, ewt, y, N_TOK * C_DIM);
    scatter_kernel<<<(N_TOK * 2) / 256, 256, 0, stream>>>(topki, topkw, base, cursor, etok, ewt);

    gemm1_kernel<<<dim3(H_DIM / 128, 64, NGRP), 256, 0, stream>>>(xb, w1t, hbuf, etok, base, pcount);
    gemm2_kernel<<<dim3(C_DIM / 128, 64, NGRP), 256, 0, stream>>>(hbuf, w2t, y, etok, ewt, base, pcount, cnt8);
}

// Round 4
// 818.582 us; speedup vs baseline: 1.0473x; 1.0238x over previous
//
#include <hip/hip_runtime.h>
#include <hip/hip_bf16.h>
#include <math.h>

// Problem constants
#define N_TOK 4096
#define C_DIM 1024
#define H_DIM 4096
#define NEXP 7          // dynamic experts
#define NGRP 8          // 7 dynamic + 1 static
#define HCAP 13184      // max padded entries: <=13177, rounded up

typedef __attribute__((ext_vector_type(8))) short short8;
typedef __attribute__((ext_vector_type(4))) float floatx4;

// ---- workspace layout (bytes) ----
static const size_t OFF_COUNTS = 0;                                  // int[8]
static const size_t OFF_CURSOR = 64;                                 // int[8]
static const size_t OFF_BASE   = 128;                                // int[8]
static const size_t OFF_PCOUNT = 192;                                // int[8]
static const size_t OFF_CNT8   = 256;                                // int[8]
static const size_t OFF_USAGE  = 320;                                // float[8]
static const size_t OFF_TOPKI  = 4096;                               // int[8192]
static const size_t OFF_TOPKW  = OFF_TOPKI + 8192ull * 4;            // float[8192]
static const size_t OFF_ETOK   = OFF_TOPKW + 8192ull * 4;            // int[HCAP]
static const size_t OFF_EWT    = OFF_ETOK + (size_t)HCAP * 4;        // float[HCAP]
static const size_t OFF_EIDX   = OFF_EWT + (size_t)HCAP * 4;         // int[8192] token->entry map
static const size_t OFF_XB     = 262144;                             // bf16[N*C]
static const size_t OFF_W1T    = OFF_XB + (size_t)N_TOK * C_DIM * 2; // bf16[8][H][C]; reused as yp after gemm1
static const size_t OFF_W2T    = OFF_W1T + (size_t)NGRP * H_DIM * C_DIM * 2; // bf16[8][C][H]
static const size_t OFF_H      = OFF_W2T + (size_t)NGRP * C_DIM * H_DIM * 2; // bf16[HCAP][H]

static __device__ __forceinline__ unsigned short f2bf(float f) {
    __hip_bfloat16 b = __float2bfloat16(f);
    return *reinterpret_cast<unsigned short*>(&b);
}
static __device__ __forceinline__ float bf2f(unsigned short u) {
    unsigned int v = ((unsigned int)u) << 16;
    return __builtin_bit_cast(float, v);
}

// exact-gelu via A&S 7.1.26 erf approx (|err|<=1.5e-7)
static __device__ __forceinline__ float gelu_f(float v) {
    float z = v * 0.70710678118654752f;
    float az = fabsf(z);
    float t = 1.0f / (1.0f + 0.3275911f * az);
    float poly = t * (0.254829592f + t * (-0.284496736f + t * (1.421413741f +
                 t * (-1.453152027f + t * 1.061405429f))));
    float erf_abs = 1.0f - poly * __expf(-az * az);
    float erf_v = (z < 0.f) ? -erf_abs : erf_abs;
    return 0.5f * v * (1.0f + erf_v);
}

static __device__ __forceinline__ void gll16(const void* g, void* l) {
    __builtin_amdgcn_global_load_lds((const __attribute__((address_space(1))) void*)g,
                                     (__attribute__((address_space(3))) void*)l, 16, 0, 0);
}

// ---------------- small init ----------------
__global__ void init_small_kernel(int* counts, int* cursor, float* usage) {
    int i = threadIdx.x;
    if (i < 8) { counts[i] = 0; cursor[i] = 0; usage[i] = 0.f; }
}

// ---------------- x fp32 -> bf16 ----------------
__global__ void convert_x_kernel(const float* __restrict__ x, unsigned short* __restrict__ xb) {
    int i = blockIdx.x * 256 + threadIdx.x;   // i < N*C/4
    float4 v = ((const float4*)x)[i];
    ushort4 o;
    o.x = f2bf(v.x); o.y = f2bf(v.y); o.z = f2bf(v.z); o.w = f2bf(v.w);
    ((ushort4*)xb)[i] = o;
}

// ---------------- transpose + convert: src[R,S] fp32 -> dst[S,R] bf16, 8 experts ----
// tile: 64 rows (R) x 32 cols (S); writes are 128B-wide (64 consecutive bf16)
__global__ __launch_bounds__(256) void transpose_cvt_kernel(
    const float* __restrict__ dyn, const float* __restrict__ stat,
    __hip_bfloat16* __restrict__ dst, int R, int S)
{
    int e = blockIdx.z;
    const float* src = (e < NEXP) ? (dyn + (size_t)e * R * S) : stat;
    __hip_bfloat16* d = dst + (size_t)e * R * S;
    int s0 = blockIdx.x * 32, r0 = blockIdx.y * 64;
    int tx = threadIdx.x & 31, ty = threadIdx.x >> 5; // 32 x 8
    __shared__ float t[64][33];
#pragma unroll
    for (int i = 0; i < 8; i++) {
        int r = ty + i * 8;
        t[r][tx] = src[(size_t)(r0 + r) * S + s0 + tx];
    }
    __syncthreads();
    int tx2 = threadIdx.x & 63, ty2 = threadIdx.x >> 6; // 64 x 4
#pragma unroll
    for (int i = 0; i < 8; i++) {
        int s = ty2 + i * 4;
        d[(size_t)(s0 + s) * R + r0 + tx2] = __float2bfloat16(t[tx2][s]);
    }
}

// ---------------- gating: one wave per token ----------------
__global__ __launch_bounds__(256) void gate_kernel(
    const float* __restrict__ x, const float* __restrict__ gw,
    int* __restrict__ topki, float* __restrict__ topkw,
    int* counts, float* usage)
{
    int wid = threadIdx.x >> 6, lane = threadIdx.x & 63;
    int t = blockIdx.x * 4 + wid;
    float s[NEXP];
#pragma unroll
    for (int e = 0; e < NEXP; e++) s[e] = 0.f;
    for (int c = lane; c < C_DIM; c += 64) {
        float xv = x[(size_t)t * C_DIM + c];
#pragma unroll
        for (int e = 0; e < NEXP; e++) s[e] += xv * gw[c * NEXP + e];
    }
#pragma unroll
    for (int e = 0; e < NEXP; e++)
        for (int off = 32; off > 0; off >>= 1) s[e] += __shfl_xor(s[e], off);
    if (lane == 0) {
        int e0 = 0;
        for (int e = 1; e < NEXP; e++) if (s[e] > s[e0]) e0 = e;
        int e1 = -1;
        for (int e = 0; e < NEXP; e++) {
            if (e == e0) continue;
            if (e1 < 0 || s[e] > s[e1]) e1 = e;
        }
        float w0 = 1.f / (1.f + expf(s[e1] - s[e0]));
        float w1 = 1.f - w0;
        topki[t * 2] = e0; topki[t * 2 + 1] = e1;
        topkw[t * 2] = w0; topkw[t * 2 + 1] = w1;
        atomicAdd(&counts[e0], 1); atomicAdd(&counts[e1], 1);
        atomicAdd(&usage[e0], w0); atomicAdd(&usage[e1], w1);
    }
}

// ---------------- prefix: group bases, pads, static entries, aux loss ----------------
__global__ __launch_bounds__(256) void prefix_kernel(
    const int* counts, const float* usage,
    int* base, int* pcount, int* cnt8,
    int* etok, float* ewt, float* y, int aux_index)
{
    __shared__ int sb[NGRP], sc[NGRP], sp[NGRP];
    if (threadIdx.x == 0) {
        int run = 0;
        for (int g = 0; g < NEXP; g++) {
            int c = counts[g];
            int p = (c + 127) & ~127;
            base[g] = run; pcount[g] = p; cnt8[g] = c;
            sb[g] = run; sc[g] = c; sp[g] = p;
            run += p;
        }
        base[NEXP] = run; pcount[NEXP] = N_TOK; cnt8[NEXP] = N_TOK;
        sb[NEXP] = run; sc[NEXP] = N_TOK; sp[NEXP] = N_TOK;
        // aux = 0.01 * variance(expert_usage)
        float u[NEXP]; float mean = 0.f;
        for (int e = 0; e < NEXP; e++) { u[e] = usage[e] / (float)N_TOK; mean += u[e]; }
        mean /= (float)NEXP;
        float var = 0.f;
        for (int e = 0; e < NEXP; e++) { float d = u[e] - mean; var += d * d; }
        var /= (float)NEXP;
        y[aux_index] = 0.01f * var;
    }
    __syncthreads();
    // static group entries: token == position, weight 1
    for (int i = threadIdx.x; i < N_TOK; i += 256) {
        etok[sb[NEXP] + i] = i; ewt[sb[NEXP] + i] = 1.0f;
    }
    // pad entries: token 0, weight 0
    for (int g = 0; g < NEXP; g++) {
        for (int i = sc[g] + (int)threadIdx.x; i < sp[g]; i += 256) {
            etok[sb[g] + i] = 0; ewt[sb[g] + i] = 0.f;
        }
    }
}

// ---------------- scatter into compact entry lists (+ inverse map) ----------------
__global__ void scatter_kernel(const int* __restrict__ topki, const float* __restrict__ topkw,
                               const int* __restrict__ base, int* cursor,
                               int* __restrict__ etok, float* __restrict__ ewt,
                               int* __restrict__ eidx)
{
    int i = blockIdx.x * 256 + threadIdx.x;   // < 8192
    int t = i >> 1;
    int e = topki[i];
    float w = topkw[i];
    int pos = atomicAdd(&cursor[e], 1);
    int idx = base[e] + pos;
    etok[idx] = t; ewt[idx] = w;
    eidx[i] = idx;
}

// ---------------- grouped GEMM1: h = gelu(X @ W1[g]) ----------------
// BK=64 staged as 2x 8KB panels; grid: (H/128, 64, 8); block 256
__global__ __launch_bounds__(256) void gemm1_kernel(
    const __hip_bfloat16* __restrict__ xb,
    const __hip_bfloat16* __restrict__ w1t,   // [8][H][C]
    __hip_bfloat16* __restrict__ h,           // [HCAP][H]
    const int* __restrict__ etok,
    const int* __restrict__ base,
    const int* __restrict__ pcount)
{
    int g = blockIdx.z, mt = blockIdx.y, ct = blockIdx.x;
    if (mt * 128 >= pcount[g]) return;
    int eb = base[g];

    __shared__ __align__(16) char AlsB[2 * 8192];
    __shared__ __align__(16) char BlsB[2 * 8192];

    int tid = threadIdx.x;
    int lane = tid & 63, wid = tid >> 6;
    int quad = lane >> 4, l16 = lane & 15;
    int wm = wid >> 1, wn = wid & 1;
    int rsub = lane >> 2, chunk = lane & 3;

    const char* gA[2]; const char* gB[2];
    char* lA[2]; char* lB[2];
#pragma unroll
    for (int j = 0; j < 2; j++) {
        int rowA = wid * 32 + j * 16 + rsub;
        int tok = etok[eb + mt * 128 + rowA];
        gA[j] = (const char*)(xb + (size_t)tok * C_DIM) + chunk * 16;
        lA[j] = AlsB + (wid * 32 + j * 16) * 64;
        int rowB = wid * 32 + j * 16 + rsub;
        gB[j] = (const char*)(w1t + ((size_t)g * H_DIM + ct * 128 + rowB) * C_DIM) + chunk * 16;
        lB[j] = BlsB + (wid * 32 + j * 16) * 64;
    }

    floatx4 acc[4][4] = {};
    for (int k0 = 0; k0 < C_DIM; k0 += 64) {
        size_t koff = (size_t)k0 * 2;
#pragma unroll
        for (int s = 0; s < 2; s++) {
            size_t so = koff + (size_t)s * 64;   // 32 k-elems * 2B
            gll16(gA[0] + so, lA[0] + s * 8192);
            gll16(gA[1] + so, lA[1] + s * 8192);
            gll16(gB[0] + so, lB[0] + s * 8192);
            gll16(gB[1] + so, lB[1] + s * 8192);
        }
        __syncthreads();
#pragma unroll
        for (int s = 0; s < 2; s++) {
            short8 a[4], b[4];
#pragma unroll
            for (int i = 0; i < 4; i++) {
                a[i] = *(const short8*)(AlsB + s * 8192 + (((wm * 64 + i * 16 + l16) * 32 + quad * 8) * 2));
                b[i] = *(const short8*)(BlsB + s * 8192 + (((wn * 64 + i * 16 + l16) * 32 + quad * 8) * 2));
            }
#pragma unroll
            for (int i = 0; i < 4; i++)
#pragma unroll
                for (int j = 0; j < 4; j++)
                    acc[i][j] = __builtin_amdgcn_mfma_f32_16x16x32_bf16(a[i], b[j], acc[i][j], 0, 0, 0);
        }
        __syncthreads();
    }

    // epilogue: fast exact-gelu poly, bf16 store to h
#pragma unroll
    for (int i = 0; i < 4; i++) {
        int rbase = mt * 128 + wm * 64 + i * 16 + quad * 4;
#pragma unroll
        for (int reg = 0; reg < 4; reg++) {
            size_t hrow = (size_t)(eb + rbase + reg) * H_DIM;
#pragma unroll
            for (int j = 0; j < 4; j++) {
                int cc = ct * 128 + wn * 64 + j * 16 + l16;
                h[hrow + cc] = __float2bfloat16(gelu_f(acc[i][j][reg]));
            }
        }
    }
}

// ---------------- grouped GEMM2: yp[entry] = H[entry] @ W2[g]  (plain stores, no atomics) ----
// BK=64 staged as 2x 8KB panels; grid: (C/128, 64, 8); block 256
__global__ __launch_bounds__(256) void gemm2_kernel(
    const __hip_bfloat16* __restrict__ h,
    const __hip_bfloat16* __restrict__ w2t,   // [8][C][H]
    unsigned short* __restrict__ yp,          // bf16 [HCAP][C]
    const int* __restrict__ base,
    const int* __restrict__ pcount)
{
    int g = blockIdx.z, ct = blockIdx.x, mt = blockIdx.y;
    if (mt * 128 >= pcount[g]) return;
    int eb = base[g];

    __shared__ __align__(16) char AlsB[2 * 8192];
    __shared__ __align__(16) char BlsB[2 * 8192];

    int tid = threadIdx.x;
    int lane = tid & 63, wid = tid >> 6;
    int quad = lane >> 4, l16 = lane & 15;
    int wm = wid >> 1, wn = wid & 1;
    int rsub = lane >> 2, chunk = lane & 3;

    const char* gA[2]; const char* gB[2];
    char* lA[2]; char* lB[2];
#pragma unroll
    for (int j = 0; j < 2; j++) {
        int rowA = wid * 32 + j * 16 + rsub;
        gA[j] = (const char*)(h + (size_t)(eb + mt * 128 + rowA) * H_DIM) + chunk * 16;
        lA[j] = AlsB + (wid * 32 + j * 16) * 64;
        int rowB = wid * 32 + j * 16 + rsub;
        gB[j] = (const char*)(w2t + ((size_t)g * C_DIM + ct * 128 + rowB) * H_DIM) + chunk * 16;
        lB[j] = BlsB + (wid * 32 + j * 16) * 64;
    }

    floatx4 acc[4][4] = {};
    for (int k0 = 0; k0 < H_DIM; k0 += 64) {
        size_t koff = (size_t)k0 * 2;
#pragma unroll
        for (int s = 0; s < 2; s++) {
            size_t so = koff + (size_t)s * 64;
            gll16(gA[0] + so, lA[0] + s * 8192);
            gll16(gA[1] + so, lA[1] + s * 8192);
            gll16(gB[0] + so, lB[0] + s * 8192);
            gll16(gB[1] + so, lB[1] + s * 8192);
        }
        __syncthreads();
#pragma unroll
        for (int s = 0; s < 2; s++) {
            short8 a[4], b[4];
#pragma unroll
            for (int i = 0; i < 4; i++) {
                a[i] = *(const short8*)(AlsB + s * 8192 + (((wm * 64 + i * 16 + l16) * 32 + quad * 8) * 2));
                b[i] = *(const short8*)(BlsB + s * 8192 + (((wn * 64 + i * 16 + l16) * 32 + quad * 8) * 2));
            }
#pragma unroll
            for (int i = 0; i < 4; i++)
#pragma unroll
                for (int j = 0; j < 4; j++)
                    acc[i][j] = __builtin_amdgcn_mfma_f32_16x16x32_bf16(a[i], b[j], acc[i][j], 0, 0, 0);
        }
        __syncthreads();
    }

    // epilogue: raw bf16 stores to yp (pad rows written too; combine never reads them)
#pragma unroll
    for (int i = 0; i < 4; i++) {
        int rl0 = mt * 128 + wm * 64 + i * 16 + quad * 4;
#pragma unroll
        for (int reg = 0; reg < 4; reg++) {
            size_t yrow = (size_t)(eb + rl0 + reg) * C_DIM;
#pragma unroll
            for (int j = 0; j < 4; j++) {
                int cc = ct * 128 + wn * 64 + j * 16 + l16;
                yp[yrow + cc] = f2bf(acc[i][j][reg]);
            }
        }
    }
}

// ---------------- combine: y[t] = w0*yp[i0] + w1*yp[i1] + yp[static+t] ----------------
__global__ __launch_bounds__(256) void combine_kernel(
    const unsigned short* __restrict__ yp,
    const int* __restrict__ eidx,
    const float* __restrict__ topkw,
    const int* __restrict__ base,
    float* __restrict__ y)
{
    int t = blockIdx.x;
    int i0 = eidx[t * 2], i1 = eidx[t * 2 + 1];
    float w0 = topkw[t * 2], w1 = topkw[t * 2 + 1];
    int is = base[NEXP] + t;
    int c = threadIdx.x * 4;
    ushort4 a = *(const ushort4*)(yp + (size_t)i0 * C_DIM + c);
    ushort4 b = *(const ushort4*)(yp + (size_t)i1 * C_DIM + c);
    ushort4 s = *(const ushort4*)(yp + (size_t)is * C_DIM + c);
    float4 o;
    o.x = w0 * bf2f(a.x) + w1 * bf2f(b.x) + bf2f(s.x);
    o.y = w0 * bf2f(a.y) + w1 * bf2f(b.y) + bf2f(s.y);
    o.z = w0 * bf2f(a.z) + w1 * bf2f(b.z) + bf2f(s.z);
    o.w = w0 * bf2f(a.w) + w1 * bf2f(b.w) + bf2f(s.w);
    *(float4*)(y + (size_t)t * C_DIM + c) = o;
}

extern "C" void kernel_launch(void* const* d_in, const int* in_sizes, int n_in,
                              void* d_out, int out_size, void* d_ws, size_t ws_size,
                              hipStream_t stream) {
    const float* x      = (const float*)d_in[0];
    const float* gate_w = (const float*)d_in[1];
    const float* w1     = (const float*)d_in[2];
    const float* w2     = (const float*)d_in[3];
    const float* w1s    = (const float*)d_in[4];
    const float* w2s    = (const float*)d_in[5];
    float* y = (float*)d_out;
    char* ws = (char*)d_ws;

    int*   counts = (int*)(ws + OFF_COUNTS);
    int*   cursor = (int*)(ws + OFF_CURSOR);
    int*   base   = (int*)(ws + OFF_BASE);
    int*   pcount = (int*)(ws + OFF_PCOUNT);
    int*   cnt8   = (int*)(ws + OFF_CNT8);
    float* usage  = (float*)(ws + OFF_USAGE);
    int*   topki  = (int*)(ws + OFF_TOPKI);
    float* topkw  = (float*)(ws + OFF_TOPKW);
    int*   etok   = (int*)(ws + OFF_ETOK);
    float* ewt    = (float*)(ws + OFF_EWT);
    int*   eidx   = (int*)(ws + OFF_EIDX);
    unsigned short* xb_u = (unsigned short*)(ws + OFF_XB);
    __hip_bfloat16* xb  = (__hip_bfloat16*)(ws + OFF_XB);
    __hip_bfloat16* w1t = (__hip_bfloat16*)(ws + OFF_W1T);
    __hip_bfloat16* w2t = (__hip_bfloat16*)(ws + OFF_W2T);
    __hip_bfloat16* hbuf = (__hip_bfloat16*)(ws + OFF_H);
    unsigned short* yp  = (unsigned short*)(ws + OFF_W1T);  // aliases w1t (dead after gemm1)

    init_small_kernel<<<1, 64, 0, stream>>>(counts, cursor, usage);

    convert_x_kernel<<<(N_TOK * C_DIM / 4) / 256, 256, 0, stream>>>(x, xb_u);
    // w1 [C,H] -> w1t [H,C]; w1s likewise as expert 7
    transpose_cvt_kernel<<<dim3(H_DIM / 32, C_DIM / 64, NGRP), 256, 0, stream>>>(w1, w1s, w1t, C_DIM, H_DIM);
    // w2 [H,C] -> w2t [C,H]; w2s likewise as expert 7
    transpose_cvt_kernel<<<dim3(C_DIM / 32, H_DIM / 64, NGRP), 256, 0, stream>>>(w2, w2s, w2t, H_DIM, C_DIM);

    gate_kernel<<<N_TOK / 4, 256, 0, stream>>>(x, gate_w, topki, topkw, counts, usage);
    prefix_kernel<<<1, 256, 0, stream>>>(counts, usage, base, pcount, cnt8, etok, ewt, y, N_TOK * C_DIM);
    scatter_kernel<<<(N_TOK * 2) / 256, 256, 0, stream>>>(topki, topkw, base, cursor, etok, ewt, eidx);

    gemm1_kernel<<<dim3(H_DIM / 128, 64, NGRP), 256, 0, stream>>>(xb, w1t, hbuf, etok, base, pcount);
    gemm2_kernel<<<dim3(C_DIM / 128, 64, NGRP), 256, 0, stream>>>(hbuf, w2t, yp, base, pcount);
    combine_kernel<<<N_TOK, 256, 0, stream>>>(yp, eidx, topkw, base, y);
}